// Round 5
// baseline (155.001 us; speedup 1.0000x reference)
//
#include <hip/hip_runtime.h>
#include <hip/hip_bf16.h>

#define NATC 10000
#define NNC 32
#define RSNC 16
#define THETANC 8
#define NEMBC 4
#define FEATC 576

typedef __attribute__((ext_vector_type(8))) short short8;  // 8 bf16 (4 VGPRs)
typedef __attribute__((ext_vector_type(4))) float f32x4;

static __device__ __forceinline__ short f2bf(float x) {
    union { __hip_bfloat16 h; short s; } u;
    u.h = __float2bfloat16(x);
    return u.s;
}

// ---------------------------------------------------------------------------
// Kernel 0: pack W1 (576x64) into bf16 MFMA B-fragment order.
// B-frag for 16x16x32: lane l needs W[k = ks*32 + (l>>4)*8 + jj][n = nt*16 + (l&15)]
// stored contiguously: W1p[((ks*4+nt)*64 + l)*8 + jj].  18 ks x 4 nt x 64 l.
// ---------------------------------------------------------------------------
__global__ __launch_bounds__(256) void prep_kernel(
    const float* __restrict__ W1, ushort* __restrict__ W1p)
{
    const int gid = blockIdx.x * 256 + threadIdx.x;   // 0..4607
    const int l = gid & 63, ntks = gid >> 6;
    const int nt = ntks & 3, ks = ntks >> 2;
    const int q = l >> 4, c = l & 15;
    ushort pk[8];
    #pragma unroll
    for (int jj = 0; jj < 8; ++jj)
        pk[jj] = (ushort)f2bf(W1[(ks * 32 + q * 8 + jj) * 64 + nt * 16 + c]);
    #pragma unroll
    for (int jj = 0; jj < 8; ++jj) W1p[gid * 8 + jj] = pk[jj];
}

// ---------------------------------------------------------------------------
// Kernel 1: FUSED per-atom descriptor + MLP. One block (256 thr = 4 waves)
// per atom. Descriptor phases as round 4 (MFMA contraction), then the 576-
// feature row stays in LDS (bf16 drow) and the MLP runs in-block:
//   layer1: wave w = n-tile, 18 m=1 MFMAs (A row0 = drow chunk, rows 1-15 =0)
//   layer2+3: wave 0, VALU matvec + tanh + dot(W3) + wave reduce.
// Output: e_atom[i] (fp32) to workspace; no global desc traffic at all.
// P stride 66 (was 65): epilogue read bank = (8q+2r+c)%32 -> 2-way (free).
// ---------------------------------------------------------------------------
__global__ __launch_bounds__(256, 4) void desc_kernel(
    const float* __restrict__ pos,
    const float* __restrict__ spe,
    const float* __restrict__ theta_s,
    const float* __restrict__ kn_rad,
    const int* __restrict__ nidx,
    const ushort* __restrict__ W1p,
    const float* __restrict__ b1,
    const float* __restrict__ W2,
    const float* __restrict__ b2,
    const float* __restrict__ W3,
    const float* __restrict__ b3,
    float* __restrict__ e_atom)
{
    constexpr float RC = 5.0f;
    constexpr float PI_F = 3.14159265358979323846f;
    constexpr float PREF = 3.0517578125e-05f; // 2^(1-16)

    __shared__ __attribute__((aligned(16))) float ux[NNC], uy[NNC], uz[NNC];
    __shared__ __attribute__((aligned(16))) float rbase[NNC], rw[NNC];
    __shared__ __attribute__((aligned(16))) float bfs[NNC * 17];
    __shared__ __attribute__((aligned(16))) float ses[NNC * 5];
    __shared__ __attribute__((aligned(16))) float P[NNC * 66];      // fp32, pad 66
    __shared__ __attribute__((aligned(16))) float cosm[NNC * 33];
    __shared__ __attribute__((aligned(16))) float sinm[NNC * 33];
    __shared__ __attribute__((aligned(16))) short Pb[4 * 64 * 8];   // bf16 B-frags
    __shared__ __attribute__((aligned(16))) ushort drow[FEATC];     // bf16 desc row
    __shared__ __attribute__((aligned(16))) float h1p[64];          // layer1 partials
    __shared__ __attribute__((aligned(16))) float h1f[64];          // tanh(h1)

    const int i   = blockIdx.x;
    const int tid = threadIdx.x;

    // --- phase 0: bond geometry (32 threads) ---
    if (tid < NNC) {
        const int j = tid;
        const int n = nidx[i * NNC + j];
        const float pix = pos[i * 3 + 0], piy = pos[i * 3 + 1], piz = pos[i * 3 + 2];
        const float dx = pos[n * 3 + 0] - pix;
        const float dy = pos[n * 3 + 1] - piy;
        const float dz = pos[n * 3 + 2] - piz;
        const float r = sqrtf(dx * dx + dy * dy + dz * dz) + 1e-8f;
        const float inv = 1.0f / r;
        ux[j] = dx * inv; uy[j] = dy * inv; uz[j] = dz * inv;
        const float fc = (r < RC) ? 0.5f * (cosf(PI_F * r * (1.0f / RC)) + 1.0f) : 0.0f;
        rbase[j] = sqrtf(2.0f / RC) * inv * fc;
        rw[j]    = (PI_F / RC) * kn_rad[0] * r;
        #pragma unroll
        for (int m = 0; m < NEMBC; ++m)
            ses[j * 5 + m] = spe[n * NEMBC + m] * spe[i * NEMBC + m];
    }
    __syncthreads();

    // --- phase 1: bessel basis (512 items) ---
    #pragma unroll
    for (int k = 0; k < 2; ++k) {
        const int e = tid + k * 256;
        const int j = e >> 4, l = e & 15;
        bfs[j * 17 + l] = rbase[j] * sinf(rw[j] * (float)(l + 1));
    }
    __syncthreads();

    // --- phase 2: P fp32 (stride 66) + cos/sin matrix (stride 33) ---
    #pragma unroll
    for (int k = 0; k < 8; ++k) {
        const int e = tid + k * 256;
        const int j = e >> 6, p = e & 63;
        P[j * 66 + p] = bfs[j * 17 + (p >> 2)] * ses[j * 5 + (p & 3)];
    }
    #pragma unroll
    for (int k = 0; k < 4; ++k) {
        const int idx = tid + k * 256;
        const int j = idx >> 5, kk = idx & 31;
        float c = ux[j] * ux[kk] + uy[j] * uy[kk] + uz[j] * uz[kk];
        c = fminf(fmaxf(c, -1.0f + 1e-6f), 1.0f - 1e-6f);
        cosm[j * 33 + kk] = c;
        sinm[j * 33 + kk] = sqrtf(fmaxf(1.0f - c * c, 0.0f));
    }
    __syncthreads();

    // --- phase 3: pack Pb (bf16 B-frags) + radial descriptor into drow ---
    {
        const int nt = tid >> 6, l2 = tid & 63;
        const int q2 = l2 >> 4, c2 = l2 & 15;
        short8 pk;
        #pragma unroll
        for (int jj = 0; jj < 8; ++jj)
            pk[jj] = f2bf(P[(q2 * 8 + jj) * 66 + nt * 16 + c2]);
        *(short8*)&Pb[(nt * 64 + l2) * 8] = pk;
    }
    if (tid < 64) {
        float s = 0.0f;
        #pragma unroll 8
        for (int j = 0; j < NNC; ++j) s += P[j * 66 + tid];
        drow[tid] = (ushort)f2bf(s);
    }
    __syncthreads();

    // --- phase 4: MFMA angular contraction per theta ---
    const int w = tid >> 6, l = tid & 63;
    const int q = l >> 4, c = l & 15;

    for (int tt = 0; tt < 2; ++tt) {
        const int t = w + tt * 4;
        const float th = theta_s[t];
        const float ct = cosf(th), st = sinf(th);

        short8 afr[2];
        #pragma unroll
        for (int mt = 0; mt < 2; ++mt) {
            const int kk = mt * 16 + c;
            #pragma unroll
            for (int jj = 0; jj < 8; ++jj) {
                const int j = q * 8 + jj;
                const float cv = cosm[kk * 33 + j];
                const float sv = sinm[kk * 33 + j];
                const float cosd = fmaf(cv, ct, sv * st);
                const float x = 1.0f + cosd;
                const float x2 = x * x, x4 = x2 * x2, x8 = x4 * x4;
                afr[mt][jj] = f2bf(PREF * (x8 * x8));
            }
        }

        f32x4 acc[2][4];
        #pragma unroll
        for (int mt = 0; mt < 2; ++mt)
            #pragma unroll
            for (int nt = 0; nt < 4; ++nt)
                acc[mt][nt] = (f32x4){0.0f, 0.0f, 0.0f, 0.0f};

        #pragma unroll
        for (int nt = 0; nt < 4; ++nt) {
            const short8 bfr = *(const short8*)&Pb[(nt * 64 + l) * 8];
            acc[0][nt] = __builtin_amdgcn_mfma_f32_16x16x32_bf16(afr[0], bfr, acc[0][nt], 0, 0, 0);
            acc[1][nt] = __builtin_amdgcn_mfma_f32_16x16x32_bf16(afr[1], bfr, acc[1][nt], 0, 0, 0);
        }

        float pt[4];
        #pragma unroll
        for (int nt = 0; nt < 4; ++nt) {
            float s = 0.0f;
            #pragma unroll
            for (int mt = 0; mt < 2; ++mt)
                #pragma unroll
                for (int r = 0; r < 4; ++r) {
                    const int kk = mt * 16 + q * 4 + r;
                    s = fmaf(acc[mt][nt][r], P[kk * 66 + nt * 16 + c], s);
                }
            s += __shfl_xor(s, 16, 64);
            s += __shfl_xor(s, 32, 64);
            pt[nt] = s;
        }
        const float v = (q == 0) ? pt[0] : (q == 1) ? pt[1] : (q == 2) ? pt[2] : pt[3];
        drow[64 + t * 64 + l] = (ushort)f2bf(v);
    }
    __syncthreads();

    // --- phase 5: layer1 via m=1 MFMA. wave w = n-tile (n = w*16 + c). ---
    {
        f32x4 acc1 = (f32x4){0.0f, 0.0f, 0.0f, 0.0f};
        const short8 zero8 = (short8){0, 0, 0, 0, 0, 0, 0, 0};
        #pragma unroll 3
        for (int ks = 0; ks < 18; ++ks) {
            const short8 bfr = *(const short8*)&W1p[((ks * 4 + w) * 64 + l) * 8];
            short8 afr = *(const short8*)&drow[ks * 32 + q * 8];
            if (c != 0) afr = zero8;          // only A row 0 is real
            acc1 = __builtin_amdgcn_mfma_f32_16x16x32_bf16(afr, bfr, acc1, 0, 0, 0);
        }
        if (l < 16) h1p[w * 16 + l] = acc1[0];   // D row 0 = lanes 0..15, reg 0
    }
    __syncthreads();

    // --- phase 6: tanh + layer2 + layer3 on wave 0; one store per atom ---
    if (tid < 64) {
        h1f[tid] = tanhf(h1p[tid] + b1[tid]);
        float acc2 = b2[tid];
        #pragma unroll 8
        for (int k = 0; k < 64; ++k)
            acc2 = fmaf(h1f[k], W2[k * 64 + tid], acc2);
        float s = tanhf(acc2) * W3[tid];
        #pragma unroll
        for (int off = 1; off <= 32; off <<= 1)
            s += __shfl_xor(s, off, 64);
        if (tid == 0) e_atom[i] = s + b3[0];
    }
}

// ---------------------------------------------------------------------------
// Kernel 2: deterministic single-block reduction of 10000 atom energies.
// ---------------------------------------------------------------------------
__global__ __launch_bounds__(256) void reduce_kernel(
    const float* __restrict__ e_atom, float* __restrict__ out)
{
    __shared__ float red[4];
    const int tid = threadIdx.x;
    float s = 0.0f;
    for (int idx = tid; idx < NATC / 4; idx += 256) {
        const float4 v = *(const float4*)&e_atom[idx * 4];
        s += (v.x + v.y) + (v.z + v.w);
    }
    #pragma unroll
    for (int off = 1; off <= 32; off <<= 1)
        s += __shfl_xor(s, off, 64);
    if ((tid & 63) == 0) red[tid >> 6] = s;
    __syncthreads();
    if (tid == 0) out[0] = (red[0] + red[1]) + (red[2] + red[3]);
}

extern "C" void kernel_launch(void* const* d_in, const int* in_sizes, int n_in,
                              void* d_out, int out_size, void* d_ws, size_t ws_size,
                              hipStream_t stream)
{
    const float* pos   = (const float*)d_in[0];
    const float* spe   = (const float*)d_in[1];
    const float* theta = (const float*)d_in[2];
    const float* kn    = (const float*)d_in[3];
    const float* W1    = (const float*)d_in[4];
    const float* b1    = (const float*)d_in[5];
    const float* W2    = (const float*)d_in[6];
    const float* b2    = (const float*)d_in[7];
    const float* W3    = (const float*)d_in[8];
    const float* b3    = (const float*)d_in[9];
    const int*   nidx  = (const int*)d_in[10];
    float* out = (float*)d_out;

    // workspace: e_atom [10000 f32] | W1p [4608*8 u16]
    float*  e_atom = (float*)d_ws;
    ushort* W1p    = (ushort*)((char*)d_ws + 40000);

    prep_kernel<<<18, 256, 0, stream>>>(W1, W1p);
    desc_kernel<<<NATC, 256, 0, stream>>>(pos, spe, theta, kn, nidx,
                                          W1p, b1, W2, b2, W3, b3, e_atom);
    reduce_kernel<<<1, 256, 0, stream>>>(e_atom, out);
}